// Round 10
// baseline (2078.191 us; speedup 1.0000x reference)
//
#include <hip/hip_runtime.h>
#include <hip/hip_bf16.h>

#define N_NODES 200000
#define N_EDGES 600000
#define NODE_IN 32
#define EDGE_IN 16
#define HID     128
#define LN_EPS  1e-5f
#define SCAN_B  512
#define NBLK_SCAN 391            // ceil(200000/512)

typedef __attribute__((ext_vector_type(8))) short short8;   // 8 bf16 (4 VGPRs)
typedef __attribute__((ext_vector_type(4))) float f32x4;    // MFMA C/D frag

// fp32 -> bf16 round-to-nearest-even (finite values)
static __device__ __forceinline__ ushort f2b(float f) {
    unsigned u = __builtin_bit_cast(unsigned, f);
    unsigned r = (u + 0x7fffu + ((u >> 16) & 1u)) >> 16;
    return (ushort)r;
}
static __device__ __forceinline__ float b2f(ushort us) {
    unsigned u = ((unsigned)us) << 16;
    return __builtin_bit_cast(float, u);
}

// ================= CSR build (once; graph is static; proven r9) =================
__global__ __launch_bounds__(256) void k_csr_zero(int* __restrict__ deg)
{
    const int i = blockIdx.x * 256 + threadIdx.x;
    if (i < N_NODES) deg[i] = 0;
}

__global__ __launch_bounds__(256) void k_csr_deg(
    const int* __restrict__ ei, int* __restrict__ deg)
{
    const int e = blockIdx.x * 256 + threadIdx.x;
    if (e < N_EDGES) atomicAdd(&deg[ei[N_EDGES + e]], 1);   // dst
}

__global__ __launch_bounds__(SCAN_B) void k_scan1(
    const int* __restrict__ deg, int* __restrict__ part)
{
    __shared__ int s[SCAN_B];
    const int t = threadIdx.x, i = blockIdx.x * SCAN_B + t;
    s[t] = (i < N_NODES) ? deg[i] : 0;
    __syncthreads();
    for (int off = SCAN_B / 2; off; off >>= 1) {
        if (t < off) s[t] += s[t + off];
        __syncthreads();
    }
    if (t == 0) part[blockIdx.x] = s[0];
}

__global__ void k_scan2(int* __restrict__ part, int* __restrict__ rowptr)
{
    if (threadIdx.x == 0) {
        int run = 0;
        for (int b = 0; b < NBLK_SCAN; b++) { int x = part[b]; part[b] = run; run += x; }
        rowptr[N_NODES] = N_EDGES;
    }
}

__global__ __launch_bounds__(SCAN_B) void k_scan3(
    const int* __restrict__ deg, const int* __restrict__ part,
    int* __restrict__ rowptr, int* __restrict__ cursor)
{
    __shared__ int s[SCAN_B];
    const int t = threadIdx.x, i = blockIdx.x * SCAN_B + t;
    const int v = (i < N_NODES) ? deg[i] : 0;
    s[t] = v;
    __syncthreads();
    for (int off = 1; off < SCAN_B; off <<= 1) {        // Hillis-Steele inclusive
        int x = (t >= off) ? s[t - off] : 0;
        __syncthreads();
        s[t] += x;
        __syncthreads();
    }
    if (i < N_NODES) {
        const int ex = s[t] - v + part[blockIdx.x];     // exclusive prefix
        rowptr[i] = ex;
        cursor[i] = ex;
    }
}

__global__ __launch_bounds__(256) void k_csr_fill(
    const int* __restrict__ ei, int* __restrict__ cursor, int* __restrict__ eid)
{
    const int e = blockIdx.x * 256 + threadIdx.x;
    if (e < N_EDGES) {
        const int slot = atomicAdd(&cursor[ei[N_EDGES + e]], 1);
        eid[slot] = e;
    }
}

// ================= weight packing (bf16 MFMA B-frags; proven) =================
__global__ __launch_bounds__(256) void k_prep_g(
    const float* __restrict__ gw1, const float* __restrict__ gw2,
    ushort* __restrict__ wpk)
{
    const int gidx = blockIdx.x * 256 + threadIdx.x;   // 0..12287
    const int m    = gidx >> 11;                       // matrix 0..5
    const int r    = gidx & 2047;
    const int lane = r & 63;
    const int ntkb = r >> 6;                           // 0..31
    const int nt = ntkb & 7, kb = ntkb >> 3;
    const int n  = nt * 16 + (lane & 15);
    const int k0 = kb * 32 + (lane >> 4) * 8;
    const float* W = (m < 3) ? gw1 + (size_t)m * HID * HID
                             : gw2 + (size_t)(m - 3) * HID * HID;
    short8 v;
#pragma unroll
    for (int j = 0; j < 8; j++)
        v[j] = (short)f2b(W[(size_t)(k0 + j) * HID + n]);
    ((short8*)wpk)[gidx] = v;
}

__global__ __launch_bounds__(256) void k_prep_m(
    const float* __restrict__ mw1, ushort* __restrict__ w1p)
{
    const int gidx = blockIdx.x * 256 + threadIdx.x;   // 0..6143
    const int lane = gidx & 63;
    const int ntkb = gidx >> 6;                        // 0..95
    const int nt = ntkb & 7, kb = ntkb >> 3;
    const int n  = nt * 16 + (lane & 15);
    const int k0 = kb * 32 + (lane >> 4) * 8;
    short8 v;
#pragma unroll
    for (int j = 0; j < 8; j++)
        v[j] = (short)f2b(mw1[(size_t)(k0 + j) * HID + n]);
    ((short8*)w1p)[gidx] = v;
}

// ---- node encoder: hb = bf16(x@enc_w+enc_b); zero red ----
__global__ __launch_bounds__(256) void k_node_enc(
    const float* __restrict__ x, const float* __restrict__ w,
    const float* __restrict__ b, ushort* __restrict__ hb,
    float* __restrict__ red)
{
    __shared__ float sx[16][NODE_IN];           // 2 KB
    const int tid = threadIdx.x;
    const int n0  = blockIdx.x * 16;
    float* sxf = &sx[0][0];
    sxf[tid]       = x[(size_t)n0 * NODE_IN + tid];
    sxf[tid + 256] = x[(size_t)n0 * NODE_IN + tid + 256];

    const int f   = tid & 127;
    const int grp = tid >> 7;                   // 0..1
    float wcol[NODE_IN];
#pragma unroll
    for (int k = 0; k < NODE_IN; k++) wcol[k] = w[k * HID + f];
    const float bf = b[f];
    __syncthreads();

#pragma unroll
    for (int it = 0; it < 8; it++) {
        const int ln = it * 2 + grp;
        const int n  = n0 + ln;
        const float4* sx4 = (const float4*)sx[ln];
        float acc = bf;
#pragma unroll
        for (int k4 = 0; k4 < NODE_IN / 4; k4++) {
            float4 v = sx4[k4];
            acc += v.x * wcol[k4*4] + v.y * wcol[k4*4+1] +
                   v.z * wcol[k4*4+2] + v.w * wcol[k4*4+3];
        }
        hb[(size_t)n * HID + f] = f2b(acc);
    }
    if (blockIdx.x == 0 && tid == 0) { red[0] = 0.f; red[1] = 0.f; }
}

// ==== FUSED aggregation + GEMM1: block owns 64 dst nodes ====
// sZ = (1+eps)*hb[n0..n0+63]; edge-parallel msg accumulation via LDS atomics;
// then z = relu(sZ @ W1 + b1) via MFMA, written bf16.
__global__ __launch_bounds__(256) void k_ag1(
    const ushort* __restrict__ hb, const int* __restrict__ ei,
    const float* __restrict__ ea, const float* __restrict__ eew,
    const float* __restrict__ eeb, const float* __restrict__ epsp,
    const int* __restrict__ rowptr, const int* __restrict__ eid,
    const short8* __restrict__ wp, const float* __restrict__ bias,
    ushort* __restrict__ z)
{
    __shared__ float sZ[64][132];               // 33.8 KB (pad 4 -> spread banks)
    const int tid = threadIdx.x;
    const int n0  = blockIdx.x * 64;
    const float alpha = 1.0f + epsp[0];

    // ---- seed: sZ = alpha * h (bf16 source, coalesced) ----
    const short8* hb8 = (const short8*)(hb + (size_t)n0 * HID);
#pragma unroll
    for (int it = 0; it < 4; it++) {
        const int q = it * 256 + tid;           // 0..1023 short8
        const int r = q >> 4, c8 = q & 15;
        short8 v = hb8[q];
#pragma unroll
        for (int j = 0; j < 8; j++)
            sZ[r][c8 * 8 + j] = alpha * b2f((ushort)v[j]);
    }
    __syncthreads();

    // ---- edge-parallel aggregation: 4 waves stride the CSR range ----
    const int lane = tid & 63;
    const int wv   = tid >> 6;
    const int f0   = lane * 2;                  // this lane's 2 features
    float2 wc[EDGE_IN];
#pragma unroll
    for (int k = 0; k < EDGE_IN; k++) {
        wc[k].x = eew[k * HID + f0];
        wc[k].y = eew[k * HID + f0 + 1];
    }
    const float bf0 = eeb[f0], bf1 = eeb[f0 + 1];

    const int jbeg = rowptr[n0], jend = rowptr[n0 + 64];
    for (int j = jbeg + wv; j < jend; j += 4) {
        const int e  = eid[j];                  // wave-uniform
        const int sn = ei[e];                   // src
        const int dl = ei[N_EDGES + e] - n0;    // local dst 0..63
        const unsigned hv = *(const unsigned*)(hb + (size_t)sn * HID + f0);
        const float h0 = b2f((ushort)(hv & 0xffffu));
        const float h1 = b2f((ushort)(hv >> 16));
        const float4* ea4 = (const float4*)(ea + (size_t)e * EDGE_IN);
        float4 a0 = ea4[0], a1 = ea4[1], a2 = ea4[2], a3 = ea4[3];
        float ev0 = bf0 + a0.x*wc[0].x + a0.y*wc[1].x + a0.z*wc[2].x + a0.w*wc[3].x
                        + a1.x*wc[4].x + a1.y*wc[5].x + a1.z*wc[6].x + a1.w*wc[7].x
                        + a2.x*wc[8].x + a2.y*wc[9].x + a2.z*wc[10].x + a2.w*wc[11].x
                        + a3.x*wc[12].x + a3.y*wc[13].x + a3.z*wc[14].x + a3.w*wc[15].x;
        float ev1 = bf1 + a0.x*wc[0].y + a0.y*wc[1].y + a0.z*wc[2].y + a0.w*wc[3].y
                        + a1.x*wc[4].y + a1.y*wc[5].y + a1.z*wc[6].y + a1.w*wc[7].y
                        + a2.x*wc[8].y + a2.y*wc[9].y + a2.z*wc[10].y + a2.w*wc[11].y
                        + a3.x*wc[12].y + a3.y*wc[13].y + a3.z*wc[14].y + a3.w*wc[15].y;
        atomicAdd(&sZ[dl][f0],     fmaxf(h0 + ev0, 0.f));
        atomicAdd(&sZ[dl][f0 + 1], fmaxf(h1 + ev1, 0.f));
    }
    __syncthreads();

    // ---- MFMA GEMM1 from fp32 LDS (cvt to bf16 frags) ----
    const int r0   = wv * 16;
    const int arow = r0 + (lane & 15);
    const int kg8  = (lane >> 4) * 8;
    f32x4 acc[8] = {};
    for (int kb = 0; kb < 4; kb++) {
        short8 af;
#pragma unroll
        for (int j = 0; j < 8; j++)
            af[j] = (short)f2b(sZ[arow][kb * 32 + kg8 + j]);
#pragma unroll
        for (int nt = 0; nt < 8; nt++) {
            short8 bf8 = wp[(kb * 8 + nt) * 64 + lane];
            acc[nt] = __builtin_amdgcn_mfma_f32_16x16x32_bf16(af, bf8, acc[nt], 0, 0, 0);
        }
    }

    const int rowb = n0 + r0 + (lane >> 4) * 4;
#pragma unroll
    for (int nt = 0; nt < 8; nt++) {
        const int c = nt * 16 + (lane & 15);
        const float bc = bias[c];
#pragma unroll
        for (int j = 0; j < 4; j++) {
            float o = fmaxf(acc[nt][j] + bc, 0.f);       // relu (gemm1)
            z[(size_t)(rowb + j) * HID + c] = f2b(o);
        }
    }
}

// -------- MFMA GEMM [Mx128]@[128x128]+bias -> bf16 out (IN-PLACE SAFE; proven) ----
template<bool IN_BF16, bool RELU_OUT, bool REDUCE>
__global__ __launch_bounds__(256) void k_gemm(
    const void* in_, const short8* __restrict__ wp,
    const float* __restrict__ bias, ushort* out, float* __restrict__ red)
{
    __shared__ ushort sU[64][136];              // 17408 B
    const int tid = threadIdx.x;
    const int m0  = blockIdx.x * 64;

    if constexpr (IN_BF16) {
        const short8* in8 = (const short8*)((const ushort*)in_ + (size_t)m0 * HID);
#pragma unroll
        for (int it = 0; it < 4; it++) {
            const int q = it * 256 + tid;       // 0..1023
            const int r = q >> 4, c8 = q & 15;
            *(short8*)&sU[r][c8 * 8] = in8[q];
        }
    } else {
        const float4* in4 = (const float4*)((const float*)in_ + (size_t)m0 * HID);
#pragma unroll
        for (int it = 0; it < 8; it++) {
            const int q = it * 256 + tid;       // 0..2047
            const int r = q >> 5, c4 = q & 31;
            float4 v = in4[q];
            ushort4 u;
            u.x = f2b(v.x); u.y = f2b(v.y); u.z = f2b(v.z); u.w = f2b(v.w);
            *(ushort4*)&sU[r][c4 * 4] = u;
        }
    }
    __syncthreads();

    const int lane = tid & 63;
    const int r0   = (tid >> 6) * 16;           // wave's 16 rows
    const int arow = r0 + (lane & 15);
    const int kg8  = (lane >> 4) * 8;
    f32x4 acc[8] = {};
    for (int kb = 0; kb < 4; kb++) {
        short8 af = *(const short8*)&sU[arow][kb * 32 + kg8];
#pragma unroll
        for (int nt = 0; nt < 8; nt++) {
            short8 bf8 = wp[(kb * 8 + nt) * 64 + lane];
            acc[nt] = __builtin_amdgcn_mfma_f32_16x16x32_bf16(af, bf8, acc[nt], 0, 0, 0);
        }
    }

    float lsum = 0.f, lsq = 0.f;
    const int rowb = m0 + r0 + (lane >> 4) * 4;
#pragma unroll
    for (int nt = 0; nt < 8; nt++) {
        const int c = nt * 16 + (lane & 15);
        const float bc = bias[c];
#pragma unroll
        for (int j = 0; j < 4; j++) {
            float o = acc[nt][j] + bc;
            if constexpr (RELU_OUT) o = fmaxf(o, 0.f);
            if constexpr (REDUCE) { lsum += o; lsq += o * o; }
            out[(size_t)(rowb + j) * HID + c] = f2b(o);
        }
    }

    if constexpr (REDUCE) {
#pragma unroll
        for (int off = 32; off; off >>= 1) {
            lsum += __shfl_down(lsum, off);
            lsq  += __shfl_down(lsq, off);
        }
        __shared__ float sws[4], swq[4];
        const int wid = tid >> 6;
        if ((tid & 63) == 0) { sws[wid] = lsum; swq[wid] = lsq; }
        __syncthreads();
        if (tid == 0) {
            atomicAdd(&red[0], sws[0] + sws[1] + sws[2] + sws[3]);
            atomicAdd(&red[1], swq[0] + swq[1] + swq[2] + swq[3]);
        }
    }
}

// ---- LN finalize ----
__global__ void k_lnfin(float* __restrict__ red)
{
    if (threadIdx.x == 0) {
        const float inv = 1.0f / ((float)N_NODES * (float)HID);
        const float mu  = red[0] * inv;
        const float var = red[1] * inv - mu * mu;
        red[2] = mu;
        red[3] = 1.0f / sqrtf(var + LN_EPS);
        red[0] = 0.f; red[1] = 0.f;
    }
}

// ---- LN apply + relu: hb = bf16(relu((z-mu)*rstd*g + b)) ----
__global__ __launch_bounds__(256) void k_ln(
    const ushort* __restrict__ z, const float* __restrict__ red,
    const float* __restrict__ g, const float* __restrict__ b,
    ushort* __restrict__ hb)
{
    const float mu = red[2], rstd = red[3];
    const int i = blockIdx.x * 256 + threadIdx.x;    // 0..NH/8-1
    short8 z8 = ((const short8*)z)[i];
    const int cb = (i & 15) * 2;                     // float4 idx into g/b
    float4 g0 = ((const float4*)g)[cb],  g1 = ((const float4*)g)[cb + 1];
    float4 b0 = ((const float4*)b)[cb],  b1 = ((const float4*)b)[cb + 1];
    short8 h8;
    h8[0] = (short)f2b(fmaxf((b2f((ushort)z8[0]) - mu) * rstd * g0.x + b0.x, 0.f));
    h8[1] = (short)f2b(fmaxf((b2f((ushort)z8[1]) - mu) * rstd * g0.y + b0.y, 0.f));
    h8[2] = (short)f2b(fmaxf((b2f((ushort)z8[2]) - mu) * rstd * g0.z + b0.z, 0.f));
    h8[3] = (short)f2b(fmaxf((b2f((ushort)z8[3]) - mu) * rstd * g0.w + b0.w, 0.f));
    h8[4] = (short)f2b(fmaxf((b2f((ushort)z8[4]) - mu) * rstd * g1.x + b1.x, 0.f));
    h8[5] = (short)f2b(fmaxf((b2f((ushort)z8[5]) - mu) * rstd * g1.y + b1.y, 0.f));
    h8[6] = (short)f2b(fmaxf((b2f((ushort)z8[6]) - mu) * rstd * g1.z + b1.z, 0.f));
    h8[7] = (short)f2b(fmaxf((b2f((ushort)z8[7]) - mu) * rstd * g1.w + b1.w, 0.f));
    ((short8*)hb)[i] = h8;
}

// ---- final MLP via MFMA; h A-frags gathered straight to registers (proven r9) ----
__global__ __launch_bounds__(256) void k_mlp(
    const ushort* __restrict__ hb, const int* __restrict__ ei,
    const float* __restrict__ ea, const float* __restrict__ eew,
    const float* __restrict__ eeb,
    const ushort* __restrict__ w1p, const float* __restrict__ b1,
    const float* __restrict__ w2, const float* __restrict__ b2,
    float* __restrict__ out)
{
    __shared__ ushort sE[64][136];              // edge features only, 17408 B
    const int* __restrict__ src = ei;
    const int* __restrict__ dst = ei + N_EDGES;
    const int tid = threadIdx.x;
    const int e0  = blockIdx.x * 64;
    const int lane = tid & 63;
    const int wv   = tid >> 6;                  // 0..3
    const int r0   = wv * 16;

    // ---- stage recomputed edge features (128 bf16 per edge) ----
    {
        const int f = tid & 127;
        float wcol[EDGE_IN];
#pragma unroll
        for (int k = 0; k < EDGE_IN; k++) wcol[k] = eew[k * HID + f];
        const float bf = eeb[f];
#pragma unroll
        for (int it = 0; it < 32; it++) {
            const int e = it * 2 + (tid >> 7);  // wave-uniform
            const float4* ea4 = (const float4*)(ea + (size_t)(e0 + e) * EDGE_IN);
            float ev = bf;
#pragma unroll
            for (int k4 = 0; k4 < EDGE_IN / 4; k4++) {
                float4 v = ea4[k4];
                ev += v.x * wcol[k4*4] + v.y * wcol[k4*4+1] +
                      v.z * wcol[k4*4+2] + v.w * wcol[k4*4+3];
            }
            sE[e][f] = f2b(ev);
        }
    }

    // ---- prefetch h A-frags for this wave straight to registers ----
    const int er = e0 + r0 + (lane & 15);       // this lane's edge row
    const int kg = lane >> 4;                   // k-group 0..3
    const int ns = src[er], nd = dst[er];
    const short8* hb8 = (const short8*)hb;      // node row = 16 chunks of 16B
    short8 af[8];
#pragma unroll
    for (int kb = 0; kb < 4; kb++) af[kb]     = hb8[(size_t)ns * 16 + kb * 4 + kg];
#pragma unroll
    for (int kb = 0; kb < 4; kb++) af[4 + kb] = hb8[(size_t)nd * 16 + kb * 4 + kg];
    __syncthreads();

    // ---- MFMA: 16 edges x 128 hidden, K=384 ----
    f32x4 acc[8] = {};
    const short8* bfr = (const short8*)w1p;
#pragma unroll
    for (int kb = 0; kb < 8; kb++) {
#pragma unroll
        for (int nt = 0; nt < 8; nt++) {
            short8 bfrag = bfr[(kb * 8 + nt) * 64 + lane];
            acc[nt] = __builtin_amdgcn_mfma_f32_16x16x32_bf16(af[kb], bfrag, acc[nt], 0, 0, 0);
        }
    }
#pragma unroll
    for (int kb = 8; kb < 12; kb++) {
        short8 ae = *(const short8*)&sE[r0 + (lane & 15)][(kb - 8) * 32 + kg * 8];
#pragma unroll
        for (int nt = 0; nt < 8; nt++) {
            short8 bfrag = bfr[(kb * 8 + nt) * 64 + lane];
            acc[nt] = __builtin_amdgcn_mfma_f32_16x16x32_bf16(ae, bfrag, acc[nt], 0, 0, 0);
        }
    }

    // ---- epilogue: relu(+b1) dot w2, reduce hidden in-register ----
    float s0 = 0.f, s1 = 0.f, s2 = 0.f, s3 = 0.f;
#pragma unroll
    for (int nt = 0; nt < 8; nt++) {
        const int col = nt * 16 + (lane & 15);
        const float b1c = b1[col];
        const float w2c = w2[col];
        s0 += fmaxf(acc[nt][0] + b1c, 0.f) * w2c;
        s1 += fmaxf(acc[nt][1] + b1c, 0.f) * w2c;
        s2 += fmaxf(acc[nt][2] + b1c, 0.f) * w2c;
        s3 += fmaxf(acc[nt][3] + b1c, 0.f) * w2c;
    }
#pragma unroll
    for (int m = 1; m < 16; m <<= 1) {
        s0 += __shfl_xor(s0, m); s1 += __shfl_xor(s1, m);
        s2 += __shfl_xor(s2, m); s3 += __shfl_xor(s3, m);
    }
    if ((lane & 15) == 0) {
        const float bb = b2[0];
        const int eb = e0 + r0 + kg * 4;
        out[eb + 0] = s0 + bb; out[eb + 1] = s1 + bb;
        out[eb + 2] = s2 + bb; out[eb + 3] = s3 + bb;
    }
}

// ------------------------------------------------------------------
extern "C" void kernel_launch(void* const* d_in, const int* in_sizes, int n_in,
                              void* d_out, int out_size, void* d_ws, size_t ws_size,
                              hipStream_t stream)
{
    const float* x    = (const float*)d_in[0];
    const int*   ei   = (const int*)  d_in[1];
    const float* ea   = (const float*)d_in[2];
    const float* encw = (const float*)d_in[3];
    const float* encb = (const float*)d_in[4];
    const float* eew  = (const float*)d_in[5];
    const float* eeb  = (const float*)d_in[6];
    const float* gw1  = (const float*)d_in[7];
    const float* gb1  = (const float*)d_in[8];
    const float* gw2  = (const float*)d_in[9];
    const float* gb2  = (const float*)d_in[10];
    const float* geps = (const float*)d_in[11];
    const float* lng  = (const float*)d_in[12];
    const float* lnb  = (const float*)d_in[13];
    const float* mw1  = (const float*)d_in[14];
    const float* mb1  = (const float*)d_in[15];
    const float* mw2  = (const float*)d_in[16];
    const float* mb2  = (const float*)d_in[17];

    float* ws = (float*)d_ws;
    const size_t NH = (size_t)N_NODES * HID;    // 25,600,000
    ushort* hb  = (ushort*)ws;                  // bf16 [NH]: node state
    ushort* z   = (ushort*)(ws + NH / 2);       // bf16 [NH]: z1 -> z2 (in-place gemm2)
    int*    csr = (int*)(ws + NH);              // CSR area (4.8 MB)
    float*  red = ws + NH + 1300000;            // [sum, sumsq, mu, rstd]
    ushort* wpk = (ushort*)(ws + NH + 1300016); // 6 x 32 KB packed layer weights
    ushort* w1p = (ushort*)(ws + NH + 1350000); // packed mlp_w1 (196 KB)
    // total ws usage ~108 MB, well under the proven 204.8 MB

    int* deg    = csr;                          // [200000]
    int* rowptr = csr + 200000;                 // [200001]
    int* cursor = csr + 400064;                 // [200000]
    int* eid    = csr + 600064;                 // [600000]
    int* part   = csr + 1200064;                // [512]

    // ---- one-time: weight packing + CSR build + encoder ----
    k_prep_g<<<48, 256, 0, stream>>>(gw1, gw2, wpk);
    k_prep_m<<<24, 256, 0, stream>>>(mw1, w1p);
    k_csr_zero<<<(N_NODES + 255) / 256, 256, 0, stream>>>(deg);
    k_csr_deg<<<(N_EDGES + 255) / 256, 256, 0, stream>>>(ei, deg);
    k_scan1<<<NBLK_SCAN, SCAN_B, 0, stream>>>(deg, part);
    k_scan2<<<1, 64, 0, stream>>>(part, rowptr);
    k_scan3<<<NBLK_SCAN, SCAN_B, 0, stream>>>(deg, part, rowptr, cursor);
    k_csr_fill<<<(N_EDGES + 255) / 256, 256, 0, stream>>>(ei, cursor, eid);
    k_node_enc<<<N_NODES / 16, 256, 0, stream>>>(x, encw, encb, hb, red);

    const int LN_BLKS = (int)(NH / 8 / 256);    // 12500
    for (int l = 0; l < 3; l++) {
        k_ag1<<<N_NODES / 64, 256, 0, stream>>>(
            hb, ei, ea, eew, eeb, geps + l, rowptr, eid,
            (const short8*)wpk + (size_t)l * 2048, gb1 + (size_t)l * HID, z);
        k_gemm<true, false, true><<<N_NODES / 64, 256, 0, stream>>>(
            z, (const short8*)wpk + (size_t)(3 + l) * 2048,
            gb2 + (size_t)l * HID, z, red);
        k_lnfin<<<1, 64, 0, stream>>>(red);
        k_ln<<<LN_BLKS, 256, 0, stream>>>(
            z, red, lng + (size_t)l * HID, lnb + (size_t)l * HID, hb);
    }

    k_mlp<<<N_EDGES / 64, 256, 0, stream>>>(hb, ei, ea, eew, eeb,
                                            w1p, mb1, mw2, mb2, (float*)d_out);
}

// Round 11
// 1570.714 us; speedup vs baseline: 1.3231x; 1.3231x over previous
//
#include <hip/hip_runtime.h>
#include <hip/hip_bf16.h>

#define N_NODES 200000
#define N_EDGES 600000
#define NODE_IN 32
#define EDGE_IN 16
#define HID     128
#define LN_EPS  1e-5f
#define SCAN_B  512
#define NBLK_SCAN 391            // ceil(200000/512)

typedef __attribute__((ext_vector_type(8))) short short8;   // 8 bf16 (4 VGPRs)
typedef __attribute__((ext_vector_type(4))) float f32x4;    // MFMA C/D frag

// fp32 -> bf16 round-to-nearest-even (finite values)
static __device__ __forceinline__ ushort f2b(float f) {
    unsigned u = __builtin_bit_cast(unsigned, f);
    unsigned r = (u + 0x7fffu + ((u >> 16) & 1u)) >> 16;
    return (ushort)r;
}
static __device__ __forceinline__ float b2f(ushort us) {
    unsigned u = ((unsigned)us) << 16;
    return __builtin_bit_cast(float, u);
}

// ================= CSR build (once; graph static; scan proven r9) =================
__global__ __launch_bounds__(256) void k_csr_zero(int* __restrict__ deg)
{
    const int i = blockIdx.x * 256 + threadIdx.x;
    if (i < N_NODES) deg[i] = 0;
}

__global__ __launch_bounds__(256) void k_csr_deg(
    const int* __restrict__ ei, int* __restrict__ deg)
{
    const int e = blockIdx.x * 256 + threadIdx.x;
    if (e < N_EDGES) atomicAdd(&deg[ei[N_EDGES + e]], 1);   // dst
}

__global__ __launch_bounds__(SCAN_B) void k_scan1(
    const int* __restrict__ deg, int* __restrict__ part)
{
    __shared__ int s[SCAN_B];
    const int t = threadIdx.x, i = blockIdx.x * SCAN_B + t;
    s[t] = (i < N_NODES) ? deg[i] : 0;
    __syncthreads();
    for (int off = SCAN_B / 2; off; off >>= 1) {
        if (t < off) s[t] += s[t + off];
        __syncthreads();
    }
    if (t == 0) part[blockIdx.x] = s[0];
}

__global__ void k_scan2(int* __restrict__ part, int* __restrict__ rowptr)
{
    if (threadIdx.x == 0) {
        int run = 0;
        for (int b = 0; b < NBLK_SCAN; b++) { int x = part[b]; part[b] = run; run += x; }
        rowptr[N_NODES] = N_EDGES;
    }
}

__global__ __launch_bounds__(SCAN_B) void k_scan3(
    const int* __restrict__ deg, const int* __restrict__ part,
    int* __restrict__ rowptr, int* __restrict__ cursor)
{
    __shared__ int s[SCAN_B];
    const int t = threadIdx.x, i = blockIdx.x * SCAN_B + t;
    const int v = (i < N_NODES) ? deg[i] : 0;
    s[t] = v;
    __syncthreads();
    for (int off = 1; off < SCAN_B; off <<= 1) {        // Hillis-Steele inclusive
        int x = (t >= off) ? s[t - off] : 0;
        __syncthreads();
        s[t] += x;
        __syncthreads();
    }
    if (i < N_NODES) {
        const int ex = s[t] - v + part[blockIdx.x];     // exclusive prefix
        rowptr[i] = ex;
        cursor[i] = ex;
    }
}

// fill: slot-ordered src/dst and permuted edge_attr (linear reads later)
__global__ __launch_bounds__(256) void k_csr_fill(
    const int* __restrict__ ei, const float* __restrict__ ea,
    int* __restrict__ cursor, int* __restrict__ srcp,
    int* __restrict__ dstp, float* __restrict__ eap)
{
    const int e = blockIdx.x * 256 + threadIdx.x;
    if (e < N_EDGES) {
        const int d = ei[N_EDGES + e];
        const int slot = atomicAdd(&cursor[d], 1);
        srcp[slot] = ei[e];
        dstp[slot] = d;
        const float4* s4 = (const float4*)(ea + (size_t)e * EDGE_IN);
        float4* o4 = (float4*)(eap + (size_t)slot * EDGE_IN);
        o4[0] = s4[0]; o4[1] = s4[1]; o4[2] = s4[2]; o4[3] = s4[3];
    }
}

// ================= weight packing (bf16 MFMA B-frags; proven) =================
__global__ __launch_bounds__(256) void k_prep_g(
    const float* __restrict__ gw1, const float* __restrict__ gw2,
    ushort* __restrict__ wpk)
{
    const int gidx = blockIdx.x * 256 + threadIdx.x;   // 0..12287
    const int m    = gidx >> 11;                       // matrix 0..5
    const int r    = gidx & 2047;
    const int lane = r & 63;
    const int ntkb = r >> 6;                           // 0..31
    const int nt = ntkb & 7, kb = ntkb >> 3;
    const int n  = nt * 16 + (lane & 15);
    const int k0 = kb * 32 + (lane >> 4) * 8;
    const float* W = (m < 3) ? gw1 + (size_t)m * HID * HID
                             : gw2 + (size_t)(m - 3) * HID * HID;
    short8 v;
#pragma unroll
    for (int j = 0; j < 8; j++)
        v[j] = (short)f2b(W[(size_t)(k0 + j) * HID + n]);
    ((short8*)wpk)[gidx] = v;
}

__global__ __launch_bounds__(256) void k_prep_m(
    const float* __restrict__ mw1, ushort* __restrict__ w1p)
{
    const int gidx = blockIdx.x * 256 + threadIdx.x;   // 0..6143
    const int lane = gidx & 63;
    const int ntkb = gidx >> 6;                        // 0..95
    const int nt = ntkb & 7, kb = ntkb >> 3;
    const int n  = nt * 16 + (lane & 15);
    const int k0 = kb * 32 + (lane >> 4) * 8;
    short8 v;
#pragma unroll
    for (int j = 0; j < 8; j++)
        v[j] = (short)f2b(mw1[(size_t)(k0 + j) * HID + n]);
    ((short8*)w1p)[gidx] = v;
}

// ---- node encoder: acc = x@enc_w+enc_b ; hz = bf16(acc); agg = (1+eps0)*acc ----
__global__ __launch_bounds__(256) void k_node_enc(
    const float* __restrict__ x, const float* __restrict__ w,
    const float* __restrict__ b, const float* __restrict__ epsp,
    ushort* __restrict__ hz, float* __restrict__ agg,
    float* __restrict__ red)
{
    __shared__ float sx[16][NODE_IN];           // 2 KB
    const int tid = threadIdx.x;
    const int n0  = blockIdx.x * 16;
    float* sxf = &sx[0][0];
    sxf[tid]       = x[(size_t)n0 * NODE_IN + tid];
    sxf[tid + 256] = x[(size_t)n0 * NODE_IN + tid + 256];

    const int f   = tid & 127;
    const int grp = tid >> 7;                   // 0..1
    float wcol[NODE_IN];
#pragma unroll
    for (int k = 0; k < NODE_IN; k++) wcol[k] = w[k * HID + f];
    const float bf = b[f];
    const float alpha = 1.0f + epsp[0];
    __syncthreads();

#pragma unroll
    for (int it = 0; it < 8; it++) {
        const int ln = it * 2 + grp;
        const int n  = n0 + ln;
        const float4* sx4 = (const float4*)sx[ln];
        float acc = bf;
#pragma unroll
        for (int k4 = 0; k4 < NODE_IN / 4; k4++) {
            float4 v = sx4[k4];
            acc += v.x * wcol[k4*4] + v.y * wcol[k4*4+1] +
                   v.z * wcol[k4*4+2] + v.w * wcol[k4*4+3];
        }
        hz[(size_t)n * HID + f]  = f2b(acc);
        agg[(size_t)n * HID + f] = alpha * acc;
    }
    if (blockIdx.x == 0 && tid == 0) { red[0] = 0.f; red[1] = 0.f; }
}

// ---- slot-ordered message scatter with run-length-reduced atomics ----
// thread = (8 contiguous slots) x (1 feature); dst-runs flushed once.
__global__ __launch_bounds__(256) void k_msg2(
    const ushort* __restrict__ hz, const int* __restrict__ srcp,
    const int* __restrict__ dstp, const float* __restrict__ eap,
    const float* __restrict__ eew, const float* __restrict__ eeb,
    float* __restrict__ agg)
{
    const int tid = threadIdx.x;
    const int f   = tid & 127;
    const int s0  = blockIdx.x * 16 + (tid >> 7) * 8;

    float wcol[EDGE_IN];
#pragma unroll
    for (int k = 0; k < EDGE_IN; k++) wcol[k] = eew[k * HID + f];
    const float bf = eeb[f];

    int   prev = dstp[s0];
    float sum  = 0.f;
#pragma unroll
    for (int it = 0; it < 8; it++) {
        const int s  = s0 + it;
        const int d  = dstp[s];                 // wave-uniform
        const int sn = srcp[s];                 // wave-uniform
        const float4* e4 = (const float4*)(eap + (size_t)s * EDGE_IN);
        float4 a0 = e4[0], a1 = e4[1], a2 = e4[2], a3 = e4[3];
        float ev = bf;
        ev += a0.x*wcol[0]  + a0.y*wcol[1]  + a0.z*wcol[2]  + a0.w*wcol[3];
        ev += a1.x*wcol[4]  + a1.y*wcol[5]  + a1.z*wcol[6]  + a1.w*wcol[7];
        ev += a2.x*wcol[8]  + a2.y*wcol[9]  + a2.z*wcol[10] + a2.w*wcol[11];
        ev += a3.x*wcol[12] + a3.y*wcol[13] + a3.z*wcol[14] + a3.w*wcol[15];
        const float m = fmaxf(b2f(hz[(size_t)sn * HID + f]) + ev, 0.f);
        if (d != prev) {                        // wave-uniform branch
            atomicAdd(&agg[(size_t)prev * HID + f], sum);
            prev = d; sum = m;
        } else {
            sum += m;
        }
    }
    atomicAdd(&agg[(size_t)prev * HID + f], sum);
}

// -------- MFMA GEMM [Mx128]@[128x128]+bias -> bf16 out (IN-PLACE SAFE; proven) ----
template<bool IN_BF16, bool RELU_OUT, bool REDUCE>
__global__ __launch_bounds__(256) void k_gemm(
    const void* in_, const short8* __restrict__ wp,
    const float* __restrict__ bias, ushort* out, float* __restrict__ red)
{
    __shared__ ushort sU[64][136];              // 17408 B
    const int tid = threadIdx.x;
    const int m0  = blockIdx.x * 64;

    if constexpr (IN_BF16) {
        const short8* in8 = (const short8*)((const ushort*)in_ + (size_t)m0 * HID);
#pragma unroll
        for (int it = 0; it < 4; it++) {
            const int q = it * 256 + tid;       // 0..1023
            const int r = q >> 4, c8 = q & 15;
            *(short8*)&sU[r][c8 * 8] = in8[q];
        }
    } else {
        const float4* in4 = (const float4*)((const float*)in_ + (size_t)m0 * HID);
#pragma unroll
        for (int it = 0; it < 8; it++) {
            const int q = it * 256 + tid;       // 0..2047
            const int r = q >> 5, c4 = q & 31;
            float4 v = in4[q];
            ushort4 u;
            u.x = f2b(v.x); u.y = f2b(v.y); u.z = f2b(v.z); u.w = f2b(v.w);
            *(ushort4*)&sU[r][c4 * 4] = u;
        }
    }
    __syncthreads();

    const int lane = tid & 63;
    const int r0   = (tid >> 6) * 16;           // wave's 16 rows
    const int arow = r0 + (lane & 15);
    const int kg8  = (lane >> 4) * 8;
    f32x4 acc[8] = {};
    for (int kb = 0; kb < 4; kb++) {
        short8 af = *(const short8*)&sU[arow][kb * 32 + kg8];
#pragma unroll
        for (int nt = 0; nt < 8; nt++) {
            short8 bf8 = wp[(kb * 8 + nt) * 64 + lane];
            acc[nt] = __builtin_amdgcn_mfma_f32_16x16x32_bf16(af, bf8, acc[nt], 0, 0, 0);
        }
    }

    float lsum = 0.f, lsq = 0.f;
    const int rowb = m0 + r0 + (lane >> 4) * 4;
#pragma unroll
    for (int nt = 0; nt < 8; nt++) {
        const int c = nt * 16 + (lane & 15);
        const float bc = bias[c];
#pragma unroll
        for (int j = 0; j < 4; j++) {
            float o = acc[nt][j] + bc;
            if constexpr (RELU_OUT) o = fmaxf(o, 0.f);
            if constexpr (REDUCE) { lsum += o; lsq += o * o; }
            out[(size_t)(rowb + j) * HID + c] = f2b(o);
        }
    }

    if constexpr (REDUCE) {
#pragma unroll
        for (int off = 32; off; off >>= 1) {
            lsum += __shfl_down(lsum, off);
            lsq  += __shfl_down(lsq, off);
        }
        __shared__ float sws[4], swq[4];
        const int wid = tid >> 6;
        if ((tid & 63) == 0) { sws[wid] = lsum; swq[wid] = lsq; }
        __syncthreads();
        if (tid == 0) {
            atomicAdd(&red[0], sws[0] + sws[1] + sws[2] + sws[3]);
            atomicAdd(&red[1], swq[0] + swq[1] + swq[2] + swq[3]);
        }
    }
}

// ---- LN finalize ----
__global__ void k_lnfin(float* __restrict__ red)
{
    if (threadIdx.x == 0) {
        const float inv = 1.0f / ((float)N_NODES * (float)HID);
        const float mu  = red[0] * inv;
        const float var = red[1] * inv - mu * mu;
        red[2] = mu;
        red[3] = 1.0f / sqrtf(var + LN_EPS);
        red[0] = 0.f; red[1] = 0.f;
    }
}

// ---- LN apply + relu IN-PLACE on hz; FUSE_NEXT: agg = (1+eps')*o (proven r9-style) ----
template<bool FUSE_NEXT>
__global__ __launch_bounds__(256) void k_ln(
    ushort* hz, const float* __restrict__ red,
    const float* __restrict__ g, const float* __restrict__ b,
    const float* __restrict__ eps_next, float* __restrict__ agg)
{
    const float mu = red[2], rstd = red[3];
    const int i = blockIdx.x * 256 + threadIdx.x;    // 0..NH/8-1
    short8 z8 = ((const short8*)hz)[i];
    const int cb = (i & 15) * 2;                     // float4 idx into g/b
    float4 g0 = ((const float4*)g)[cb],  g1 = ((const float4*)g)[cb + 1];
    float4 b0 = ((const float4*)b)[cb],  b1 = ((const float4*)b)[cb + 1];
    float o[8];
    o[0] = fmaxf((b2f((ushort)z8[0]) - mu) * rstd * g0.x + b0.x, 0.f);
    o[1] = fmaxf((b2f((ushort)z8[1]) - mu) * rstd * g0.y + b0.y, 0.f);
    o[2] = fmaxf((b2f((ushort)z8[2]) - mu) * rstd * g0.z + b0.z, 0.f);
    o[3] = fmaxf((b2f((ushort)z8[3]) - mu) * rstd * g0.w + b0.w, 0.f);
    o[4] = fmaxf((b2f((ushort)z8[4]) - mu) * rstd * g1.x + b1.x, 0.f);
    o[5] = fmaxf((b2f((ushort)z8[5]) - mu) * rstd * g1.y + b1.y, 0.f);
    o[6] = fmaxf((b2f((ushort)z8[6]) - mu) * rstd * g1.z + b1.z, 0.f);
    o[7] = fmaxf((b2f((ushort)z8[7]) - mu) * rstd * g1.w + b1.w, 0.f);
    short8 h8;
#pragma unroll
    for (int j = 0; j < 8; j++) h8[j] = (short)f2b(o[j]);
    ((short8*)hz)[i] = h8;
    if constexpr (FUSE_NEXT) {
        const float a = 1.0f + eps_next[0];
        float4 A0, A1;
        A0.x = a*o[0]; A0.y = a*o[1]; A0.z = a*o[2]; A0.w = a*o[3];
        A1.x = a*o[4]; A1.y = a*o[5]; A1.z = a*o[6]; A1.w = a*o[7];
        ((float4*)agg)[i * 2]     = A0;
        ((float4*)agg)[i * 2 + 1] = A1;
    }
}

// ---- final MLP via MFMA; h A-frags gathered straight to registers (proven r9) ----
__global__ __launch_bounds__(256) void k_mlp(
    const ushort* __restrict__ hz, const int* __restrict__ ei,
    const float* __restrict__ ea, const float* __restrict__ eew,
    const float* __restrict__ eeb,
    const ushort* __restrict__ w1p, const float* __restrict__ b1,
    const float* __restrict__ w2, const float* __restrict__ b2,
    float* __restrict__ out)
{
    __shared__ ushort sE[64][136];              // edge features only, 17408 B
    const int* __restrict__ src = ei;
    const int* __restrict__ dst = ei + N_EDGES;
    const int tid = threadIdx.x;
    const int e0  = blockIdx.x * 64;
    const int lane = tid & 63;
    const int wv   = tid >> 6;                  // 0..3
    const int r0   = wv * 16;

    // ---- stage recomputed edge features (128 bf16 per edge) ----
    {
        const int f = tid & 127;
        float wcol[EDGE_IN];
#pragma unroll
        for (int k = 0; k < EDGE_IN; k++) wcol[k] = eew[k * HID + f];
        const float bf = eeb[f];
#pragma unroll
        for (int it = 0; it < 32; it++) {
            const int e = it * 2 + (tid >> 7);  // wave-uniform
            const float4* ea4 = (const float4*)(ea + (size_t)(e0 + e) * EDGE_IN);
            float ev = bf;
#pragma unroll
            for (int k4 = 0; k4 < EDGE_IN / 4; k4++) {
                float4 v = ea4[k4];
                ev += v.x * wcol[k4*4] + v.y * wcol[k4*4+1] +
                      v.z * wcol[k4*4+2] + v.w * wcol[k4*4+3];
            }
            sE[e][f] = f2b(ev);
        }
    }

    // ---- prefetch h A-frags for this wave straight to registers ----
    const int er = e0 + r0 + (lane & 15);       // this lane's edge row
    const int kg = lane >> 4;                   // k-group 0..3
    const int ns = src[er], nd = dst[er];
    const short8* hb8 = (const short8*)hz;      // node row = 16 chunks of 16B
    short8 af[8];
#pragma unroll
    for (int kb = 0; kb < 4; kb++) af[kb]     = hb8[(size_t)ns * 16 + kb * 4 + kg];
#pragma unroll
    for (int kb = 0; kb < 4; kb++) af[4 + kb] = hb8[(size_t)nd * 16 + kb * 4 + kg];
    __syncthreads();

    // ---- MFMA: 16 edges x 128 hidden, K=384 ----
    f32x4 acc[8] = {};
    const short8* bfr = (const short8*)w1p;
#pragma unroll
    for (int kb = 0; kb < 8; kb++) {
#pragma unroll
        for (int nt = 0; nt < 8; nt++) {
            short8 bfrag = bfr[(kb * 8 + nt) * 64 + lane];
            acc[nt] = __builtin_amdgcn_mfma_f32_16x16x32_bf16(af[kb], bfrag, acc[nt], 0, 0, 0);
        }
    }
#pragma unroll
    for (int kb = 8; kb < 12; kb++) {
        short8 ae = *(const short8*)&sE[r0 + (lane & 15)][(kb - 8) * 32 + kg * 8];
#pragma unroll
        for (int nt = 0; nt < 8; nt++) {
            short8 bfrag = bfr[(kb * 8 + nt) * 64 + lane];
            acc[nt] = __builtin_amdgcn_mfma_f32_16x16x32_bf16(ae, bfrag, acc[nt], 0, 0, 0);
        }
    }

    // ---- epilogue: relu(+b1) dot w2, reduce hidden in-register ----
    float s0 = 0.f, s1 = 0.f, s2 = 0.f, s3 = 0.f;
#pragma unroll
    for (int nt = 0; nt < 8; nt++) {
        const int col = nt * 16 + (lane & 15);
        const float b1c = b1[col];
        const float w2c = w2[col];
        s0 += fmaxf(acc[nt][0] + b1c, 0.f) * w2c;
        s1 += fmaxf(acc[nt][1] + b1c, 0.f) * w2c;
        s2 += fmaxf(acc[nt][2] + b1c, 0.f) * w2c;
        s3 += fmaxf(acc[nt][3] + b1c, 0.f) * w2c;
    }
#pragma unroll
    for (int m = 1; m < 16; m <<= 1) {
        s0 += __shfl_xor(s0, m); s1 += __shfl_xor(s1, m);
        s2 += __shfl_xor(s2, m); s3 += __shfl_xor(s3, m);
    }
    if ((lane & 15) == 0) {
        const float bb = b2[0];
        const int eb = e0 + r0 + kg * 4;
        out[eb + 0] = s0 + bb; out[eb + 1] = s1 + bb;
        out[eb + 2] = s2 + bb; out[eb + 3] = s3 + bb;
    }
}

// ------------------------------------------------------------------
extern "C" void kernel_launch(void* const* d_in, const int* in_sizes, int n_in,
                              void* d_out, int out_size, void* d_ws, size_t ws_size,
                              hipStream_t stream)
{
    const float* x    = (const float*)d_in[0];
    const int*   ei   = (const int*)  d_in[1];
    const float* ea   = (const float*)d_in[2];
    const float* encw = (const float*)d_in[3];
    const float* encb = (const float*)d_in[4];
    const float* eew  = (const float*)d_in[5];
    const float* eeb  = (const float*)d_in[6];
    const float* gw1  = (const float*)d_in[7];
    const float* gb1  = (const float*)d_in[8];
    const float* gw2  = (const float*)d_in[9];
    const float* gb2  = (const float*)d_in[10];
    const float* geps = (const float*)d_in[11];
    const float* lng  = (const float*)d_in[12];
    const float* lnb  = (const float*)d_in[13];
    const float* mw1  = (const float*)d_in[14];
    const float* mb1  = (const float*)d_in[15];
    const float* mw2  = (const float*)d_in[16];
    const float* mb2  = (const float*)d_in[17];

    float* ws = (float*)d_ws;
    const size_t NH = (size_t)N_NODES * HID;    // 25,600,000
    // layout (floats), total ~199.5 MB < proven 204.8 MB:
    float*  agg  = ws;                          // [NH] fp32             @ 0
    ushort* hz   = (ushort*)(ws + NH);          // [NH] bf16 h/z merged  @ NH
    float*  eap  = ws + NH + NH / 2;            // [NE*16] slot-ordered  @ 1.5NH
    int*    srcp = (int*)(ws + 48000000);       // [NE]
    int*    dstp = (int*)(ws + 48600000);       // [NE]
    int*    deg  = (int*)(ws + 49200000);       // [N]
    int*    rowp = (int*)(ws + 49400000);       // [N+1]
    int*    curs = (int*)(ws + 49600064);       // [N]
    int*    part = (int*)(ws + 49800064);       // [512]
    float*  red  = ws + 49800640;               // [4]
    ushort* wpk  = (ushort*)(ws + 49800704);    // 6*128*128 bf16
    ushort* w1p  = (ushort*)(ws + 49850000);    // 384*128 bf16

    // ---- one-time: weight packing + CSR build + encoder ----
    k_prep_g<<<48, 256, 0, stream>>>(gw1, gw2, wpk);
    k_prep_m<<<24, 256, 0, stream>>>(mw1, w1p);
    k_csr_zero<<<(N_NODES + 255) / 256, 256, 0, stream>>>(deg);
    k_csr_deg<<<(N_EDGES + 255) / 256, 256, 0, stream>>>(ei, deg);
    k_scan1<<<NBLK_SCAN, SCAN_B, 0, stream>>>(deg, part);
    k_scan2<<<1, 64, 0, stream>>>(part, rowp);
    k_scan3<<<NBLK_SCAN, SCAN_B, 0, stream>>>(deg, part, rowp, curs);
    k_csr_fill<<<(N_EDGES + 255) / 256, 256, 0, stream>>>(ei, ea, curs,
                                                          srcp, dstp, eap);
    k_node_enc<<<N_NODES / 16, 256, 0, stream>>>(x, encw, encb, geps, hz, agg, red);

    const int LN_BLKS = (int)(NH / 8 / 256);    // 12500
    for (int l = 0; l < 3; l++) {
        k_msg2<<<N_EDGES / 16, 256, 0, stream>>>(hz, srcp, dstp, eap,
                                                 eew, eeb, agg);
        k_gemm<false, true, false><<<N_NODES / 64, 256, 0, stream>>>(
            agg, (const short8*)wpk + (size_t)l * 2048,
            gb1 + (size_t)l * HID, hz, nullptr);
        k_gemm<true, false, true><<<N_NODES / 64, 256, 0, stream>>>(
            hz, (const short8*)wpk + (size_t)(3 + l) * 2048,
            gb2 + (size_t)l * HID, hz, red);
        k_lnfin<<<1, 64, 0, stream>>>(red);
        if (l < 2)
            k_ln<true><<<LN_BLKS, 256, 0, stream>>>(
                hz, red, lng + (size_t)l * HID, lnb + (size_t)l * HID,
                geps + l + 1, agg);
        else
            k_ln<false><<<LN_BLKS, 256, 0, stream>>>(
                hz, red, lng + (size_t)l * HID, lnb + (size_t)l * HID,
                nullptr, nullptr);
    }

    k_mlp<<<N_EDGES / 64, 256, 0, stream>>>(hz, ei, ea, eew, eeb,
                                            w1p, mb1, mw2, mb2, (float*)d_out);
}

// Round 12
// 1478.217 us; speedup vs baseline: 1.4059x; 1.0626x over previous
//
#include <hip/hip_runtime.h>
#include <hip/hip_bf16.h>

#define N_NODES 200000
#define N_EDGES 600000
#define NODE_IN 32
#define EDGE_IN 16
#define HID     128
#define LN_EPS  1e-5f
#define SCAN_B  512
#define NBLK_SCAN 391            // ceil(200000/512)

typedef __attribute__((ext_vector_type(8))) short short8;   // 8 bf16 (4 VGPRs)
typedef __attribute__((ext_vector_type(4))) float f32x4;    // MFMA C/D frag

// fp32 -> bf16 round-to-nearest-even (finite values)
static __device__ __forceinline__ ushort f2b(float f) {
    unsigned u = __builtin_bit_cast(unsigned, f);
    unsigned r = (u + 0x7fffu + ((u >> 16) & 1u)) >> 16;
    return (ushort)r;
}
static __device__ __forceinline__ float b2f(ushort us) {
    unsigned u = ((unsigned)us) << 16;
    return __builtin_bit_cast(float, u);
}

// ================= CSR build (once; graph static; proven r9/r11) =================
__global__ __launch_bounds__(256) void k_csr_zero(int* __restrict__ deg)
{
    const int i = blockIdx.x * 256 + threadIdx.x;
    if (i < N_NODES) deg[i] = 0;
}

__global__ __launch_bounds__(256) void k_csr_deg(
    const int* __restrict__ ei, int* __restrict__ deg)
{
    const int e = blockIdx.x * 256 + threadIdx.x;
    if (e < N_EDGES) atomicAdd(&deg[ei[N_EDGES + e]], 1);   // dst
}

__global__ __launch_bounds__(SCAN_B) void k_scan1(
    const int* __restrict__ deg, int* __restrict__ part)
{
    __shared__ int s[SCAN_B];
    const int t = threadIdx.x, i = blockIdx.x * SCAN_B + t;
    s[t] = (i < N_NODES) ? deg[i] : 0;
    __syncthreads();
    for (int off = SCAN_B / 2; off; off >>= 1) {
        if (t < off) s[t] += s[t + off];
        __syncthreads();
    }
    if (t == 0) part[blockIdx.x] = s[0];
}

__global__ void k_scan2(int* __restrict__ part, int* __restrict__ rowptr)
{
    if (threadIdx.x == 0) {
        int run = 0;
        for (int b = 0; b < NBLK_SCAN; b++) { int x = part[b]; part[b] = run; run += x; }
        rowptr[N_NODES] = N_EDGES;
    }
}

__global__ __launch_bounds__(SCAN_B) void k_scan3(
    const int* __restrict__ deg, const int* __restrict__ part,
    int* __restrict__ rowptr, int* __restrict__ cursor)
{
    __shared__ int s[SCAN_B];
    const int t = threadIdx.x, i = blockIdx.x * SCAN_B + t;
    const int v = (i < N_NODES) ? deg[i] : 0;
    s[t] = v;
    __syncthreads();
    for (int off = 1; off < SCAN_B; off <<= 1) {        // Hillis-Steele inclusive
        int x = (t >= off) ? s[t - off] : 0;
        __syncthreads();
        s[t] += x;
        __syncthreads();
    }
    if (i < N_NODES) {
        const int ex = s[t] - v + part[blockIdx.x];     // exclusive prefix
        rowptr[i] = ex;
        cursor[i] = ex;
    }
}

// fill: slot-ordered src/dst/edge-attr + slot->edge map (for mlp scatter)
__global__ __launch_bounds__(256) void k_csr_fill(
    const int* __restrict__ ei, const float* __restrict__ ea,
    int* __restrict__ cursor, int* __restrict__ srcp,
    int* __restrict__ dstp, int* __restrict__ eidp, float* __restrict__ eap)
{
    const int e = blockIdx.x * 256 + threadIdx.x;
    if (e < N_EDGES) {
        const int d = ei[N_EDGES + e];
        const int slot = atomicAdd(&cursor[d], 1);
        srcp[slot] = ei[e];
        dstp[slot] = d;
        eidp[slot] = e;
        const float4* s4 = (const float4*)(ea + (size_t)e * EDGE_IN);
        float4* o4 = (float4*)(eap + (size_t)slot * EDGE_IN);
        o4[0] = s4[0]; o4[1] = s4[1]; o4[2] = s4[2]; o4[3] = s4[3];
    }
}

// ================= weight packing (bf16 MFMA B-frags; proven) =================
__global__ __launch_bounds__(256) void k_prep_g(
    const float* __restrict__ gw1, const float* __restrict__ gw2,
    ushort* __restrict__ wpk)
{
    const int gidx = blockIdx.x * 256 + threadIdx.x;   // 0..12287
    const int m    = gidx >> 11;                       // matrix 0..5
    const int r    = gidx & 2047;
    const int lane = r & 63;
    const int ntkb = r >> 6;                           // 0..31
    const int nt = ntkb & 7, kb = ntkb >> 3;
    const int n  = nt * 16 + (lane & 15);
    const int k0 = kb * 32 + (lane >> 4) * 8;
    const float* W = (m < 3) ? gw1 + (size_t)m * HID * HID
                             : gw2 + (size_t)(m - 3) * HID * HID;
    short8 v;
#pragma unroll
    for (int j = 0; j < 8; j++)
        v[j] = (short)f2b(W[(size_t)(k0 + j) * HID + n]);
    ((short8*)wpk)[gidx] = v;
}

__global__ __launch_bounds__(256) void k_prep_m(
    const float* __restrict__ mw1, ushort* __restrict__ w1p)
{
    const int gidx = blockIdx.x * 256 + threadIdx.x;   // 0..6143
    const int lane = gidx & 63;
    const int ntkb = gidx >> 6;                        // 0..95
    const int nt = ntkb & 7, kb = ntkb >> 3;
    const int n  = nt * 16 + (lane & 15);
    const int k0 = kb * 32 + (lane >> 4) * 8;
    short8 v;
#pragma unroll
    for (int j = 0; j < 8; j++)
        v[j] = (short)f2b(mw1[(size_t)(k0 + j) * HID + n]);
    ((short8*)w1p)[gidx] = v;
}

// ---- node encoder: acc = x@enc_w+enc_b ; hz = bf16(acc); agg = (1+eps0)*acc ----
__global__ __launch_bounds__(256) void k_node_enc(
    const float* __restrict__ x, const float* __restrict__ w,
    const float* __restrict__ b, const float* __restrict__ epsp,
    ushort* __restrict__ hz, float* __restrict__ agg,
    float* __restrict__ red)
{
    __shared__ float sx[16][NODE_IN];           // 2 KB
    const int tid = threadIdx.x;
    const int n0  = blockIdx.x * 16;
    float* sxf = &sx[0][0];
    sxf[tid]       = x[(size_t)n0 * NODE_IN + tid];
    sxf[tid + 256] = x[(size_t)n0 * NODE_IN + tid + 256];

    const int f   = tid & 127;
    const int grp = tid >> 7;                   // 0..1
    float wcol[NODE_IN];
#pragma unroll
    for (int k = 0; k < NODE_IN; k++) wcol[k] = w[k * HID + f];
    const float bf = b[f];
    const float alpha = 1.0f + epsp[0];
    __syncthreads();

#pragma unroll
    for (int it = 0; it < 8; it++) {
        const int ln = it * 2 + grp;
        const int n  = n0 + ln;
        const float4* sx4 = (const float4*)sx[ln];
        float acc = bf;
#pragma unroll
        for (int k4 = 0; k4 < NODE_IN / 4; k4++) {
            float4 v = sx4[k4];
            acc += v.x * wcol[k4*4] + v.y * wcol[k4*4+1] +
                   v.z * wcol[k4*4+2] + v.w * wcol[k4*4+3];
        }
        hz[(size_t)n * HID + f]  = f2b(acc);
        agg[(size_t)n * HID + f] = alpha * acc;
    }
    if (blockIdx.x == 0 && tid == 0) { red[0] = 0.f; red[1] = 0.f; }
}

// ---- slot-ordered message scatter with run-length-reduced atomics (proven r11) ----
__global__ __launch_bounds__(256) void k_msg2(
    const ushort* __restrict__ hz, const int* __restrict__ srcp,
    const int* __restrict__ dstp, const float* __restrict__ eap,
    const float* __restrict__ eew, const float* __restrict__ eeb,
    float* __restrict__ agg)
{
    const int tid = threadIdx.x;
    const int f   = tid & 127;
    const int s0  = blockIdx.x * 16 + (tid >> 7) * 8;

    float wcol[EDGE_IN];
#pragma unroll
    for (int k = 0; k < EDGE_IN; k++) wcol[k] = eew[k * HID + f];
    const float bf = eeb[f];

    int   prev = dstp[s0];
    float sum  = 0.f;
#pragma unroll
    for (int it = 0; it < 8; it++) {
        const int s  = s0 + it;
        const int d  = dstp[s];                 // wave-uniform
        const int sn = srcp[s];                 // wave-uniform
        const float4* e4 = (const float4*)(eap + (size_t)s * EDGE_IN);
        float4 a0 = e4[0], a1 = e4[1], a2 = e4[2], a3 = e4[3];
        float ev = bf;
        ev += a0.x*wcol[0]  + a0.y*wcol[1]  + a0.z*wcol[2]  + a0.w*wcol[3];
        ev += a1.x*wcol[4]  + a1.y*wcol[5]  + a1.z*wcol[6]  + a1.w*wcol[7];
        ev += a2.x*wcol[8]  + a2.y*wcol[9]  + a2.z*wcol[10] + a2.w*wcol[11];
        ev += a3.x*wcol[12] + a3.y*wcol[13] + a3.z*wcol[14] + a3.w*wcol[15];
        const float m = fmaxf(b2f(hz[(size_t)sn * HID + f]) + ev, 0.f);
        if (d != prev) {                        // wave-uniform branch
            atomicAdd(&agg[(size_t)prev * HID + f], sum);
            prev = d; sum = m;
        } else {
            sum += m;
        }
    }
    atomicAdd(&agg[(size_t)prev * HID + f], sum);
}

// ==== FUSED GEMM1+GEMM2: z2 = relu(agg@W1+b1)@W2+b2, LN stats, bf16 out ====
// z1 never leaves LDS: each wave's gemm1 acc covers its own 16 rows x 128 cols,
// written relu+bias bf16 back into the same wave-private LDS rows.
__global__ __launch_bounds__(256) void k_gemm12(
    const float* __restrict__ in_, const short8* __restrict__ wp1,
    const float* __restrict__ bias1, const short8* __restrict__ wp2,
    const float* __restrict__ bias2, ushort* __restrict__ out,
    float* __restrict__ red)
{
    __shared__ ushort sU[64][136];              // 17408 B
    const int tid = threadIdx.x;
    const int m0  = blockIdx.x * 64;

    // stage agg fp32 -> bf16
    const float4* in4 = (const float4*)(in_ + (size_t)m0 * HID);
#pragma unroll
    for (int it = 0; it < 8; it++) {
        const int q = it * 256 + tid;           // 0..2047
        const int r = q >> 5, c4 = q & 31;
        float4 v = in4[q];
        ushort4 u;
        u.x = f2b(v.x); u.y = f2b(v.y); u.z = f2b(v.z); u.w = f2b(v.w);
        *(ushort4*)&sU[r][c4 * 4] = u;
    }
    __syncthreads();

    const int lane = tid & 63;
    const int r0   = (tid >> 6) * 16;           // wave's 16 rows
    const int arow = r0 + (lane & 15);
    const int kg8  = (lane >> 4) * 8;

    // ---- GEMM1 ----
    f32x4 acc[8] = {};
    for (int kb = 0; kb < 4; kb++) {
        short8 af = *(const short8*)&sU[arow][kb * 32 + kg8];
#pragma unroll
        for (int nt = 0; nt < 8; nt++) {
            short8 bf8 = wp1[(kb * 8 + nt) * 64 + lane];
            acc[nt] = __builtin_amdgcn_mfma_f32_16x16x32_bf16(af, bf8, acc[nt], 0, 0, 0);
        }
    }
    __syncthreads();

    // ---- z1 = relu(acc + b1) -> LDS bf16 (wave-private rows) ----
    const int rloc = r0 + (lane >> 4) * 4;      // this lane's 4 C/D rows
#pragma unroll
    for (int nt = 0; nt < 8; nt++) {
        const int c = nt * 16 + (lane & 15);
        const float bc = bias1[c];
#pragma unroll
        for (int j = 0; j < 4; j++)
            sU[rloc + j][c] = f2b(fmaxf(acc[nt][j] + bc, 0.f));
    }
    __syncthreads();

    // ---- GEMM2 ----
    f32x4 acc2[8] = {};
    for (int kb = 0; kb < 4; kb++) {
        short8 af = *(const short8*)&sU[arow][kb * 32 + kg8];
#pragma unroll
        for (int nt = 0; nt < 8; nt++) {
            short8 bf8 = wp2[(kb * 8 + nt) * 64 + lane];
            acc2[nt] = __builtin_amdgcn_mfma_f32_16x16x32_bf16(af, bf8, acc2[nt], 0, 0, 0);
        }
    }

    // ---- epilogue: bias2, LN stats, bf16 store ----
    float lsum = 0.f, lsq = 0.f;
    const int rowb = m0 + rloc;
#pragma unroll
    for (int nt = 0; nt < 8; nt++) {
        const int c = nt * 16 + (lane & 15);
        const float bc = bias2[c];
#pragma unroll
        for (int j = 0; j < 4; j++) {
            float o = acc2[nt][j] + bc;
            lsum += o; lsq += o * o;
            out[(size_t)(rowb + j) * HID + c] = f2b(o);
        }
    }
#pragma unroll
    for (int off = 32; off; off >>= 1) {
        lsum += __shfl_down(lsum, off);
        lsq  += __shfl_down(lsq, off);
    }
    __shared__ float sws[4], swq[4];
    const int wid = tid >> 6;
    if ((tid & 63) == 0) { sws[wid] = lsum; swq[wid] = lsq; }
    __syncthreads();
    if (tid == 0) {
        atomicAdd(&red[0], sws[0] + sws[1] + sws[2] + sws[3]);
        atomicAdd(&red[1], swq[0] + swq[1] + swq[2] + swq[3]);
    }
}

// ---- LN finalize ----
__global__ void k_lnfin(float* __restrict__ red)
{
    if (threadIdx.x == 0) {
        const float inv = 1.0f / ((float)N_NODES * (float)HID);
        const float mu  = red[0] * inv;
        const float var = red[1] * inv - mu * mu;
        red[2] = mu;
        red[3] = 1.0f / sqrtf(var + LN_EPS);
        red[0] = 0.f; red[1] = 0.f;
    }
}

// ---- LN apply + relu IN-PLACE on hz; FUSE_NEXT: agg = (1+eps')*o (proven) ----
template<bool FUSE_NEXT>
__global__ __launch_bounds__(256) void k_ln(
    ushort* hz, const float* __restrict__ red,
    const float* __restrict__ g, const float* __restrict__ b,
    const float* __restrict__ eps_next, float* __restrict__ agg)
{
    const float mu = red[2], rstd = red[3];
    const int i = blockIdx.x * 256 + threadIdx.x;    // 0..NH/8-1
    short8 z8 = ((const short8*)hz)[i];
    const int cb = (i & 15) * 2;                     // float4 idx into g/b
    float4 g0 = ((const float4*)g)[cb],  g1 = ((const float4*)g)[cb + 1];
    float4 b0 = ((const float4*)b)[cb],  b1 = ((const float4*)b)[cb + 1];
    float o[8];
    o[0] = fmaxf((b2f((ushort)z8[0]) - mu) * rstd * g0.x + b0.x, 0.f);
    o[1] = fmaxf((b2f((ushort)z8[1]) - mu) * rstd * g0.y + b0.y, 0.f);
    o[2] = fmaxf((b2f((ushort)z8[2]) - mu) * rstd * g0.z + b0.z, 0.f);
    o[3] = fmaxf((b2f((ushort)z8[3]) - mu) * rstd * g0.w + b0.w, 0.f);
    o[4] = fmaxf((b2f((ushort)z8[4]) - mu) * rstd * g1.x + b1.x, 0.f);
    o[5] = fmaxf((b2f((ushort)z8[5]) - mu) * rstd * g1.y + b1.y, 0.f);
    o[6] = fmaxf((b2f((ushort)z8[6]) - mu) * rstd * g1.z + b1.z, 0.f);
    o[7] = fmaxf((b2f((ushort)z8[7]) - mu) * rstd * g1.w + b1.w, 0.f);
    short8 h8;
#pragma unroll
    for (int j = 0; j < 8; j++) h8[j] = (short)f2b(o[j]);
    ((short8*)hz)[i] = h8;
    if constexpr (FUSE_NEXT) {
        const float a = 1.0f + eps_next[0];
        float4 A0, A1;
        A0.x = a*o[0]; A0.y = a*o[1]; A0.z = a*o[2]; A0.w = a*o[3];
        A1.x = a*o[4]; A1.y = a*o[5]; A1.z = a*o[6]; A1.w = a*o[7];
        ((float4*)agg)[i * 2]     = A0;
        ((float4*)agg)[i * 2 + 1] = A1;
    }
}

// ---- final MLP via MFMA, dst-sorted slot order; logits scattered via eidp ----
__global__ __launch_bounds__(256) void k_mlp(
    const ushort* __restrict__ hz, const int* __restrict__ srcp,
    const int* __restrict__ dstp, const int* __restrict__ eidp,
    const float* __restrict__ eap, const float* __restrict__ eew,
    const float* __restrict__ eeb,
    const ushort* __restrict__ w1p, const float* __restrict__ b1,
    const float* __restrict__ w2, const float* __restrict__ b2,
    float* __restrict__ out)
{
    __shared__ ushort sE[64][136];              // edge features only, 17408 B
    const int tid = threadIdx.x;
    const int e0  = blockIdx.x * 64;            // slot base
    const int lane = tid & 63;
    const int wv   = tid >> 6;                  // 0..3
    const int r0   = wv * 16;

    // ---- stage recomputed edge features (slot-linear eap reads) ----
    {
        const int f = tid & 127;
        float wcol[EDGE_IN];
#pragma unroll
        for (int k = 0; k < EDGE_IN; k++) wcol[k] = eew[k * HID + f];
        const float bf = eeb[f];
#pragma unroll
        for (int it = 0; it < 32; it++) {
            const int e = it * 2 + (tid >> 7);  // wave-uniform
            const float4* ea4 = (const float4*)(eap + (size_t)(e0 + e) * EDGE_IN);
            float ev = bf;
#pragma unroll
            for (int k4 = 0; k4 < EDGE_IN / 4; k4++) {
                float4 v = ea4[k4];
                ev += v.x * wcol[k4*4] + v.y * wcol[k4*4+1] +
                      v.z * wcol[k4*4+2] + v.w * wcol[k4*4+3];
            }
            sE[e][f] = f2b(ev);
        }
    }

    // ---- prefetch h A-frags straight to registers (dst-runs coalesce) ----
    const int slot = e0 + r0 + (lane & 15);     // this lane's slot row
    const int kg   = lane >> 4;                 // k-group 0..3
    const int ns = srcp[slot], nd = dstp[slot];
    const short8* hb8 = (const short8*)hz;      // node row = 16 chunks of 16B
    short8 af[8];
#pragma unroll
    for (int kb = 0; kb < 4; kb++) af[kb]     = hb8[(size_t)ns * 16 + kb * 4 + kg];
#pragma unroll
    for (int kb = 0; kb < 4; kb++) af[4 + kb] = hb8[(size_t)nd * 16 + kb * 4 + kg];
    __syncthreads();

    // ---- MFMA: 16 slots x 128 hidden, K=384 ----
    f32x4 acc[8] = {};
    const short8* bfr = (const short8*)w1p;
#pragma unroll
    for (int kb = 0; kb < 8; kb++) {
#pragma unroll
        for (int nt = 0; nt < 8; nt++) {
            short8 bfrag = bfr[(kb * 8 + nt) * 64 + lane];
            acc[nt] = __builtin_amdgcn_mfma_f32_16x16x32_bf16(af[kb], bfrag, acc[nt], 0, 0, 0);
        }
    }
#pragma unroll
    for (int kb = 8; kb < 12; kb++) {
        short8 ae = *(const short8*)&sE[r0 + (lane & 15)][(kb - 8) * 32 + kg * 8];
#pragma unroll
        for (int nt = 0; nt < 8; nt++) {
            short8 bfrag = bfr[(kb * 8 + nt) * 64 + lane];
            acc[nt] = __builtin_amdgcn_mfma_f32_16x16x32_bf16(ae, bfrag, acc[nt], 0, 0, 0);
        }
    }

    // ---- epilogue: relu(+b1) dot w2, reduce hidden in-register, scatter ----
    float s0 = 0.f, s1 = 0.f, s2 = 0.f, s3 = 0.f;
#pragma unroll
    for (int nt = 0; nt < 8; nt++) {
        const int col = nt * 16 + (lane & 15);
        const float b1c = b1[col];
        const float w2c = w2[col];
        s0 += fmaxf(acc[nt][0] + b1c, 0.f) * w2c;
        s1 += fmaxf(acc[nt][1] + b1c, 0.f) * w2c;
        s2 += fmaxf(acc[nt][2] + b1c, 0.f) * w2c;
        s3 += fmaxf(acc[nt][3] + b1c, 0.f) * w2c;
    }
#pragma unroll
    for (int m = 1; m < 16; m <<= 1) {
        s0 += __shfl_xor(s0, m); s1 += __shfl_xor(s1, m);
        s2 += __shfl_xor(s2, m); s3 += __shfl_xor(s3, m);
    }
    if ((lane & 15) == 0) {
        const float bb = b2[0];
        const int sb = e0 + r0 + kg * 4;
        out[eidp[sb + 0]] = s0 + bb; out[eidp[sb + 1]] = s1 + bb;
        out[eidp[sb + 2]] = s2 + bb; out[eidp[sb + 3]] = s3 + bb;
    }
}

// ------------------------------------------------------------------
extern "C" void kernel_launch(void* const* d_in, const int* in_sizes, int n_in,
                              void* d_out, int out_size, void* d_ws, size_t ws_size,
                              hipStream_t stream)
{
    const float* x    = (const float*)d_in[0];
    const int*   ei   = (const int*)  d_in[1];
    const float* ea   = (const float*)d_in[2];
    const float* encw = (const float*)d_in[3];
    const float* encb = (const float*)d_in[4];
    const float* eew  = (const float*)d_in[5];
    const float* eeb  = (const float*)d_in[6];
    const float* gw1  = (const float*)d_in[7];
    const float* gb1  = (const float*)d_in[8];
    const float* gw2  = (const float*)d_in[9];
    const float* gb2  = (const float*)d_in[10];
    const float* geps = (const float*)d_in[11];
    const float* lng  = (const float*)d_in[12];
    const float* lnb  = (const float*)d_in[13];
    const float* mw1  = (const float*)d_in[14];
    const float* mb1  = (const float*)d_in[15];
    const float* mw2  = (const float*)d_in[16];
    const float* mb2  = (const float*)d_in[17];

    float* ws = (float*)d_ws;
    const size_t NH = (size_t)N_NODES * HID;    // 25,600,000
    // layout (float offsets), total ~201.9 MB < proven 204.8 MB:
    float*  agg  = ws;                          // [NH] fp32            @ 0
    ushort* hz   = (ushort*)(ws + NH);          // [NH] bf16 h/z merged @ 25.6M
    float*  eap  = ws + NH + NH / 2;            // [NE*16]              @ 38.4M
    int*    srcp = (int*)(ws + 48000000);       // [NE]
    int*    dstp = (int*)(ws + 48600000);       // [NE]
    int*    eidp = (int*)(ws + 49200000);       // [NE] slot->edge
    int*    deg  = (int*)(ws + 49800000);       // [N]
    int*    rowp = (int*)(ws + 50000000);       // [N+1]
    int*    curs = (int*)(ws + 50200064);       // [N]
    int*    part = (int*)(ws + 50400064);       // [512]
    float*  red  = ws + 50400640;               // [4]
    ushort* wpk  = (ushort*)(ws + 50400704);    // 6*128*128 bf16
    ushort* w1p  = (ushort*)(ws + 50449856);    // 384*128 bf16

    // ---- one-time: weight packing + CSR build + encoder ----
    k_prep_g<<<48, 256, 0, stream>>>(gw1, gw2, wpk);
    k_prep_m<<<24, 256, 0, stream>>>(mw1, w1p);
    k_csr_zero<<<(N_NODES + 255) / 256, 256, 0, stream>>>(deg);
    k_csr_deg<<<(N_EDGES + 255) / 256, 256, 0, stream>>>(ei, deg);
    k_scan1<<<NBLK_SCAN, SCAN_B, 0, stream>>>(deg, part);
    k_scan2<<<1, 64, 0, stream>>>(part, rowp);
    k_scan3<<<NBLK_SCAN, SCAN_B, 0, stream>>>(deg, part, rowp, curs);
    k_csr_fill<<<(N_EDGES + 255) / 256, 256, 0, stream>>>(ei, ea, curs,
                                                          srcp, dstp, eidp, eap);
    k_node_enc<<<N_NODES / 16, 256, 0, stream>>>(x, encw, encb, geps, hz, agg, red);

    const int LN_BLKS = (int)(NH / 8 / 256);    // 12500
    for (int l = 0; l < 3; l++) {
        k_msg2<<<N_EDGES / 16, 256, 0, stream>>>(hz, srcp, dstp, eap,
                                                 eew, eeb, agg);
        k_gemm12<<<N_NODES / 64, 256, 0, stream>>>(
            agg, (const short8*)wpk + (size_t)l * 2048, gb1 + (size_t)l * HID,
            (const short8*)wpk + (size_t)(3 + l) * 2048, gb2 + (size_t)l * HID,
            hz, red);
        k_lnfin<<<1, 64, 0, stream>>>(red);
        if (l < 2)
            k_ln<true><<<LN_BLKS, 256, 0, stream>>>(
                hz, red, lng + (size_t)l * HID, lnb + (size_t)l * HID,
                geps + l + 1, agg);
        else
            k_ln<false><<<LN_BLKS, 256, 0, stream>>>(
                hz, red, lng + (size_t)l * HID, lnb + (size_t)l * HID,
                nullptr, nullptr);
    }

    k_mlp<<<N_EDGES / 64, 256, 0, stream>>>(hz, srcp, dstp, eidp, eap,
                                            eew, eeb, w1p, mb1, mw2, mb2,
                                            (float*)d_out);
}